// Round 10
// baseline (467.056 us; speedup 1.0000x reference)
//
#include <hip/hip_runtime.h>

#define HW 256
#define PW 258              // padded width/height
#define PP (PW * PW)        // padded pixels per image
#define NPIX (HW * HW)

using short8 = __attribute__((ext_vector_type(8))) short;
using short4v = __attribute__((ext_vector_type(4))) short;
using f32x4 = __attribute__((ext_vector_type(4))) float;
using h4 = __attribute__((ext_vector_type(4))) _Float16;

// async global->LDS, 16B per lane; LDS dest = wave-uniform base + lane*16
#define GLD_LDS(g, l)                                                  \
  __builtin_amdgcn_global_load_lds(                                    \
      (const __attribute__((address_space(1))) void*)(g),              \
      (__attribute__((address_space(3))) void*)(l), 16, 0, 0)

static __device__ __forceinline__ ushort f2bf(float f) {
  unsigned u = __float_as_uint(f);
  unsigned r = (u + 0x7FFFu + ((u >> 16) & 1u)) >> 16;  // RNE
  return (ushort)r;
}
static __device__ __forceinline__ float bf2f(ushort u) {
  return __uint_as_float(((unsigned)u) << 16);
}

// ---------------------------------------------------------------------------
// prep_pack_k: fused pack_in + zero_halo + data->out copy (one launch).
// ---------------------------------------------------------------------------
__global__ void prep_pack_k(const float* __restrict__ din,
                            ushort* __restrict__ xp, ushort* __restrict__ x,
                            ushort* __restrict__ y,
                            const float4* __restrict__ data4,
                            float4* __restrict__ out4) {
  int blk = blockIdx.x, tid = threadIdx.x;
  if (blk < 1024) {
    int i = blk * 256 + tid;  // 0..262143
    int b = i >> 16;
    int px = i & 65535;
    int yy = px >> 8, xx = px & 255;
    short8 v;
#pragma unroll
    for (int z = 0; z < 8; ++z) v[z] = 0;
#pragma unroll
    for (int ic = 0; ic < 6; ++ic)
      v[ic] = (short)f2bf(din[(b * 6 + ic) * NPIX + px]);
    *(short8*)&xp[((size_t)b * PP + (size_t)(yy + 1) * PW + (xx + 1)) * 8] = v;
  } else if (blk < 1041) {
    int i = (blk - 1024) * 256 + tid;
    if (i >= 4 * 1028) return;
    int b = i / 1028;
    int h = i - b * 1028;
    int py, px;
    if (h < 258) { py = 0; px = h; }
    else if (h < 516) { py = 257; px = h - 258; }
    else if (h < 772) { py = h - 516 + 1; px = 0; }
    else { py = h - 772 + 1; px = 257; }
    size_t p = (size_t)b * PP + (size_t)py * PW + px;
    short8 z;
#pragma unroll
    for (int k = 0; k < 8; ++k) z[k] = 0;
#pragma unroll
    for (int c8 = 0; c8 < 8; ++c8) {
      *(short8*)&x[p * 64 + c8 * 8] = z;
      *(short8*)&y[p * 64 + c8 * 8] = z;
    }
    *(short8*)&xp[p * 8] = z;
  } else {
    int i = (blk - 1041) * 256 + tid;
    if (i < 196608) out4[i] = data4[i];
  }
}

// ---------------------------------------------------------------------------
// prep_w_k: all 8 weight packs in one launch (MFMA A-fragment order):
//   wf[((ks*NG + g)*64 + lane)*8 + j]
//   oc = g*16 + (lane&15); k = ks*32 + (lane>>4)*8 + j; t = k/CPAD; ic = k%CPAD
// ---------------------------------------------------------------------------
struct W8 { const float* w[8]; };

static __device__ __forceinline__ void pack_one(const float* __restrict__ w,
                                                ushort* __restrict__ wf, int OC,
                                                int CIN, int CPAD, int i,
                                                int total) {
  if (i >= total) return;
  int j = i & 7;
  int lane = (i >> 3) & 63;
  int rest = i >> 9;
  int NGr = (OC > 64) ? 16 : 4;
  int g = rest % NGr;
  int ks = rest / NGr;
  int oc = g * 16 + (lane & 15);
  int k = ks * 32 + (lane >> 4) * 8 + j;
  int t = k / CPAD;
  int ic = k - t * CPAD;
  float v = 0.f;
  if (oc < OC && t < 9 && ic < CIN) v = w[(oc * CIN + ic) * 9 + t];
  wf[i] = f2bf(v);
}

__global__ void prep_w_k(W8 ws, ushort* __restrict__ base) {
  int blk = blockIdx.x, tid = threadIdx.x;
  if (blk < 24) {
    pack_one(ws.w[0], base, 64, 6, 8, blk * 256 + tid, 6144);
  } else if (blk < 888) {
    int seg = (blk - 24) / 144;               // 0..5
    int i = ((blk - 24) - seg * 144) * 256 + tid;
    pack_one(ws.w[1 + seg], base + 6144 + seg * 36864, 64, 64, 64, i, 36864);
  } else {
    int i = (blk - 888) * 256 + tid;
    pack_one(ws.w[7], base + 227328, 225, 64, 64, i, 147456);
  }
}

// ---------------------------------------------------------------------------
// Implicit-GEMM 3x3 conv, bf16 MFMA 16x16x32, padded NHWC. v3 (all-LDS):
// Block = 4 rows x 64 px, 4 waves = rows; wave = 64 oc x 64 px (4mt x 4nt,
// square tile: 512 B LDS per MFMA). ALL weights staged in LDS once per block
// (73.7 KB, zero K-loop barriers, weight L2 traffic /4 vs register scheme).
// xs chunk-major [CV][6][66] slots: B-reads are natural 16B-stride b128 —
// conflict-free, no swizzle VALU. LDS 124.4 KB -> 1 block/CU (deliberate:
// grid 1024 = 4 clean rounds, rolling depth-2 reg prefetch hides LDS lat).
// ---------------------------------------------------------------------------
template <int C, int KS, bool RELU, bool RESID>
__global__ __launch_bounds__(256, (C == 8) ? 2 : 1) void conv_mfma_k(
    const ushort* __restrict__ in, const ushort* __restrict__ wf,
    const float* __restrict__ bias, const ushort* __restrict__ resid,
    ushort* __restrict__ out) {
  constexpr int CV = C / 8;                 // 16B chunks per pixel (8 or 1)
  constexpr int XSLOT = CV * 6 * 66;        // 3168 (C=64) / 396 (C=8)
  constexpr int WSLOT = KS * 4 * 64;        // 4608 (KS=18) / 768 (KS=3)
  __shared__ __align__(16) ushort wLds[WSLOT * 8];  // 73.7 KB / 12.3 KB
  __shared__ __align__(16) ushort xs[XSLOT * 8];    // 50.7 KB / 6.3 KB

  const int tid = threadIdx.x;
  const int wave = tid >> 6, lane = tid & 63;
  const int quad = lane >> 4, l15 = lane & 15;
  const int x0 = blockIdx.x * 64, y0 = blockIdx.y * 4, b = blockIdx.z;
  const ushort* inb = in + (size_t)b * PP * C;

  // stage ALL weights (identity copy, fragment order; WSLOT % 256 == 0)
  for (int s0 = wave * 64; s0 < WSLOT; s0 += 256)
    GLD_LDS(wf + (size_t)(s0 + lane) * 8, &wLds[(size_t)s0 * 8]);

  // stage activation tile chunk-major: slot = (chunk*6 + row)*66 + col
  for (int s0 = wave * 64; s0 < XSLOT; s0 += 256) {
    int s = s0 + lane;
    if (s < XSLOT) {
      int chunk = (CV == 1) ? 0 : (s / 396);
      int rem = (CV == 1) ? s : (s - chunk * 396);
      int row = rem / 66;
      int col = rem - row * 66;
      GLD_LDS(inb + ((size_t)(y0 + row) * PW + (x0 + col)) * C + chunk * 8,
              &xs[(size_t)s0 * 8]);
    }
  }
  __syncthreads();  // the only barrier

  f32x4 acc[4][4];
#pragma unroll
  for (int mt = 0; mt < 4; ++mt)
#pragma unroll
    for (int nt = 0; nt < 4; ++nt)
#pragma unroll
      for (int r = 0; r < 4; ++r) acc[mt][nt][r] = 0.f;

  auto loadA = [&](short8* A, int ks) {
#pragma unroll
    for (int mt = 0; mt < 4; ++mt)
      A[mt] = *(const short8*)&wLds[((ks * 4 + mt) * 64 + lane) * 8];
  };
  auto loadB = [&](short8* B, int ks) {
    int t, chunk;
    if (C == 64) {
      t = ks >> 1;
      chunk = ((ks & 1) << 2) + quad;
    } else {
      t = ks * 4 + quad;
      if (t > 8) t = 8;  // dummy taps: A rows are zero
      chunk = 0;
    }
    int dy = t / 3, dx = t - (t / 3) * 3;
#pragma unroll
    for (int nt = 0; nt < 4; ++nt) {
      int col = nt * 16 + l15 + dx;
      int slot = (chunk * 6 + wave + dy) * 66 + col;
      B[nt] = *(const short8*)&xs[(size_t)slot * 8];
    }
  };

  // rolling depth-2 prefetch (3 buffers): loads for ks+2 issued before
  // MFMAs of ks -> ~156 cyc of MFMA in flight per LDS round-trip.
  short8 A[3][4], B[3][4];
  loadA(A[0], 0); loadB(B[0], 0);
  if (KS > 1) { loadA(A[1], 1); loadB(B[1], 1); }
#pragma unroll
  for (int ks = 0; ks < KS; ++ks) {
    if (ks + 2 < KS) {
      loadA(A[(ks + 2) % 3], ks + 2);
      loadB(B[(ks + 2) % 3], ks + 2);
    }
#pragma unroll
    for (int nt = 0; nt < 4; ++nt)
#pragma unroll
      for (int mt = 0; mt < 4; ++mt)
        acc[mt][nt] = __builtin_amdgcn_mfma_f32_16x16x32_bf16(
            A[ks % 3][mt], B[ks % 3][nt], acc[mt][nt], 0, 0, 0);
  }

  // epilogue: C/D layout col=l15 (pixel), row=quad*4+reg (oc)
  const int yw = y0 + wave;
#pragma unroll
  for (int mt = 0; mt < 4; ++mt) {
    const float4 bb = *(const float4*)&bias[mt * 16 + quad * 4];
#pragma unroll
    for (int nt = 0; nt < 4; ++nt) {
      int px = x0 + nt * 16 + l15;
      size_t base = ((size_t)b * PP + (size_t)(yw + 1) * PW + (px + 1)) * 64 +
                    mt * 16 + quad * 4;
      float v0 = acc[mt][nt][0] + bb.x;
      float v1 = acc[mt][nt][1] + bb.y;
      float v2 = acc[mt][nt][2] + bb.z;
      float v3 = acc[mt][nt][3] + bb.w;
      if (RELU) {
        v0 = fmaxf(v0, 0.f); v1 = fmaxf(v1, 0.f);
        v2 = fmaxf(v2, 0.f); v3 = fmaxf(v3, 0.f);
      }
      if (RESID) {
        short4v rv = *(const short4v*)&resid[base];
        v0 += bf2f((ushort)rv[0]); v1 += bf2f((ushort)rv[1]);
        v2 += bf2f((ushort)rv[2]); v3 += bf2f((ushort)rv[3]);
      }
      short4v o;
      o[0] = (short)f2bf(v0); o[1] = (short)f2bf(v1);
      o[2] = (short)f2bf(v2); o[3] = (short)f2bf(v3);
      *(short4v*)&out[base] = o;
    }
  }
}

// ---------------------------------------------------------------------------
// Fused out-conv (64->225 pad 256) + abs-softmax + 15x15 kernel-conv.
// As R9 (A register window, vectorized transposed-tap consumer) but xs is
// chunk-major [8][3][66] -> conflict-free un-swizzled B-reads.
// ---------------------------------------------------------------------------
__global__ __launch_bounds__(256, 2) void out_kc_k(
    const ushort* __restrict__ x, const ushort* __restrict__ wf,
    const float* __restrict__ b_out, const float* __restrict__ data,
    float* __restrict__ pred) {
  __shared__ __align__(16) char uni[64 * 264 * 2];  // xs (25.3KB) | coreSh alias
  __shared__ __align__(16) _Float16 dshT[3 * 80 * 20];  // [ch][col][row+pad]
  __shared__ float bsh[256];
  ushort* xs = (ushort*)uni;
  _Float16* coreSh = (_Float16*)uni;

  const int tid = threadIdx.x;
  const int wave = tid >> 6, lane = tid & 63;
  const int quad = lane >> 4, l15 = lane & 15;
  const int x0 = blockIdx.x * 64, y = blockIdx.y, b = blockIdx.z;
  const ushort* wfl = wf + (size_t)lane * 8;

  // stage x tile chunk-major: slot = (chunk*3 + row)*66 + col (1584 slots)
  for (int s0 = wave * 64; s0 < 1584; s0 += 256) {
    int s = s0 + lane;
    if (s < 1584) {
      int chunk = s / 198;
      int rem = s - chunk * 198;
      int row = rem / 66;
      int col = rem - row * 66;
      GLD_LDS(x + ((size_t)b * PP + (size_t)(y + row) * PW + (x0 + col)) * 64 +
                  chunk * 8,
              &xs[(size_t)s0 * 8]);
    }
  }
  bsh[tid] = (tid < 225) ? b_out[tid] : 0.f;
  // stage data tile transposed: dshT[(ch*80+col)*20 + r]
  for (int i = tid; i < 3 * 16 * 78; i += 256) {
    int ch = i / 1248;
    int rem = i - ch * 1248;
    int r = rem / 78;
    int col = rem - r * 78;
    int gy = y - 7 + r, gx = x0 - 7 + col;
    float v = 0.f;
    if ((unsigned)gy < (unsigned)HW && (unsigned)gx < (unsigned)HW)
      v = data[((b * 3 + ch) << 16) + (gy << 8) + gx];
    dshT[(ch * 80 + col) * 20 + r] = (_Float16)v;
  }

  // preload A window (wave w -> oc group w: g = wave*4 + mt, NG = 16)
  short8 Wa[4][4];
  auto loadA = [&](int slot, int ks) {
#pragma unroll
    for (int mt = 0; mt < 4; ++mt)
      Wa[mt][slot] =
          *(const short8*)&wfl[(size_t)((ks * 16 + wave * 4 + mt)) * 512];
  };
#pragma unroll
  for (int ks = 0; ks < 4; ++ks) loadA(ks, ks);

  __syncthreads();

  f32x4 acc[4][4];
#pragma unroll
  for (int mt = 0; mt < 4; ++mt)
#pragma unroll
    for (int nt = 0; nt < 4; ++nt)
#pragma unroll
      for (int r = 0; r < 4; ++r) acc[mt][nt][r] = 0.f;

  auto loadB = [&](short8* B, int ks) {
    int t = ks >> 1;
    int dy = t / 3, dx = t - (t / 3) * 3;
    int chunk = ((ks & 1) << 2) + quad;
#pragma unroll
    for (int nt = 0; nt < 4; ++nt) {
      int col = nt * 16 + l15 + dx;
      int slot = (chunk * 3 + dy) * 66 + col;
      B[nt] = *(const short8*)&xs[(size_t)slot * 8];
    }
  };

  short8 Bbuf[2][4];
  loadB(Bbuf[0], 0);
#pragma unroll
  for (int ks = 0; ks < 18; ++ks) {
    if (ks + 1 < 18) loadB(Bbuf[(ks + 1) & 1], ks + 1);
    const int slot = ks % 4;
#pragma unroll
    for (int nt = 0; nt < 4; ++nt)
#pragma unroll
      for (int mt = 0; mt < 4; ++mt)
        acc[mt][nt] = __builtin_amdgcn_mfma_f32_16x16x32_bf16(
            Wa[mt][slot], Bbuf[ks & 1][nt], acc[mt][nt], 0, 0, 0);
    if (ks + 4 < 18) loadA(slot, ks + 4);
  }
  __syncthreads();  // retire xs reads before aliasing as coreSh

  // producer: |core + bias| (masked -> -1e4) as fp16, row stride 264
#pragma unroll
  for (int mt = 0; mt < 4; ++mt) {
    int c0 = wave * 64 + mt * 16 + quad * 4;
#pragma unroll
    for (int nt = 0; nt < 4; ++nt) {
      int px = nt * 16 + l15;
      h4 hv;
#pragma unroll
      for (int r = 0; r < 4; ++r) {
        int c = c0 + r;
        float a = acc[mt][nt][r] + bsh[c];
        a = (c < 225) ? fabsf(a) : -1e4f;
        hv[r] = (_Float16)a;
      }
      *(h4*)&coreSh[px * 264 + c0] = hv;
    }
  }
  __syncthreads();

  // consumer: px = wave*16+l15; quad = tap-row group
  const int px = wave * 16 + l15;
  const int q = quad;
  h4 vals4[15];
#pragma unroll
  for (int k = 0; k < 15; ++k)
    vals4[k] = *(h4*)&coreSh[px * 264 + q * 60 + k * 4];

  float m = 0.f;
#pragma unroll
  for (int k = 0; k < 15; ++k)
#pragma unroll
    for (int z = 0; z < 4; ++z) m = fmaxf(m, (float)vals4[k][z]);
  m = fmaxf(m, __shfl_xor(m, 16));
  m = fmaxf(m, __shfl_xor(m, 32));

  float e[60];
  float l = 0.f;
#pragma unroll
  for (int k = 0; k < 15; ++k)
#pragma unroll
    for (int z = 0; z < 4; ++z) {
      float t = __expf((float)vals4[k][z] - m);
      e[k * 4 + z] = t;
      l += t;
    }

  float p0 = 0.f, p1 = 0.f, p2 = 0.f;
#pragma unroll
  for (int dj = 0; dj < 15; ++dj) {
    h4 d0 = *(h4*)&dshT[(0 * 80 + px + dj) * 20 + 4 * q];
    h4 d1 = *(h4*)&dshT[(1 * 80 + px + dj) * 20 + 4 * q];
    h4 d2 = *(h4*)&dshT[(2 * 80 + px + dj) * 20 + 4 * q];
#pragma unroll
    for (int rr = 0; rr < 4; ++rr) {
      float ev = e[rr * 15 + dj];
      p0 += ev * (float)d0[rr];
      p1 += ev * (float)d1[rr];
      p2 += ev * (float)d2[rr];
    }
  }
  l += __shfl_xor(l, 16);  l += __shfl_xor(l, 32);
  p0 += __shfl_xor(p0, 16); p0 += __shfl_xor(p0, 32);
  p1 += __shfl_xor(p1, 16); p1 += __shfl_xor(p1, 32);
  p2 += __shfl_xor(p2, 16); p2 += __shfl_xor(p2, 32);

  if (q == 0) {
    float inv = 1.f / l;
    int pix = (y << 8) + x0 + px;
    pred[((b * 3 + 0) << 16) + pix] = p0 * inv;
    pred[((b * 3 + 1) << 16) + pix] = p1 * inv;
    pred[((b * 3 + 2) << 16) + pix] = p2 * inv;
  }
}

extern "C" void kernel_launch(void* const* d_in, const int* in_sizes, int n_in,
                              void* d_out, int out_size, void* d_ws,
                              size_t ws_size, hipStream_t stream) {
  const float* data_with_est = (const float*)d_in[0];
  const float* data = (const float*)d_in[1];
  const float* b_first = (const float*)d_in[3];
  const float* ba[3] = {(const float*)d_in[5], (const float*)d_in[9],
                        (const float*)d_in[13]};
  const float* bb[3] = {(const float*)d_in[7], (const float*)d_in[11],
                        (const float*)d_in[15]};
  const float* b_out = (const float*)d_in[17];

  float* out = (float*)d_out;
  float* pred = out + 4 * 3 * NPIX;

  // workspace layout (ushort units)
  ushort* x = (ushort*)d_ws;                 // 4*PP*64
  ushort* y = x + (size_t)4 * PP * 64;       // 4*PP*64
  ushort* xp = y + (size_t)4 * PP * 64;      // 4*PP*8
  ushort* Wb = xp + (size_t)4 * PP * 8;      // packed weights base
  ushort* Wp1 = Wb;                          //   +0      (6144)
  ushort* Wpr = Wb + 6144;                   //   +6144   (6*36864)
  ushort* Wpo = Wb + 227328;                 //   +227328 (147456)

  // fused prep (2 launches)
  prep_pack_k<<<1809, 256, 0, stream>>>(data_with_est, xp, x, y,
                                        (const float4*)data, (float4*)out);
  W8 ws;
  ws.w[0] = (const float*)d_in[2];
  ws.w[1] = (const float*)d_in[4];  ws.w[2] = (const float*)d_in[6];
  ws.w[3] = (const float*)d_in[8];  ws.w[4] = (const float*)d_in[10];
  ws.w[5] = (const float*)d_in[12]; ws.w[6] = (const float*)d_in[14];
  ws.w[7] = (const float*)d_in[16];
  prep_w_k<<<1464, 256, 0, stream>>>(ws, Wb);

  dim3 cgrid(4, 64, 4), cblk(256);
  // first conv 6->64 (C padded to 8, K padded to 96)
  conv_mfma_k<8, 3, false, false>
      <<<cgrid, cblk, 0, stream>>>(xp, Wp1, b_first, nullptr, x);
  // 3 residual blocks
  for (int i = 0; i < 3; ++i) {
    conv_mfma_k<64, 18, true, false><<<cgrid, cblk, 0, stream>>>(
        x, Wpr + (2 * i) * 36864, ba[i], nullptr, y);
    conv_mfma_k<64, 18, false, true><<<cgrid, cblk, 0, stream>>>(
        y, Wpr + (2 * i + 1) * 36864, bb[i], x, x);
  }
  // fused out-conv + softmax + kernel-conv
  out_kc_k<<<dim3(4, HW, 4), 256, 0, stream>>>(x, Wpo, b_out, data, pred);
}